// Round 1
// baseline (251.707 us; speedup 1.0000x reference)
//
#include <hip/hip_runtime.h>

// DTW wavefront kernel for MI355X (gfx950).
// B=32, N=32, D=12, P=32, L=1024, L_OUT=32, RHO=1 => w=1 exactly.
// D[i,j] = c[i,j] + min3(D[i-1,j-1], D[i-1,j], D[i,j-1]); boundaries = BIG.
// One wave64 = 2 (b,n) problems (same b); lane-in-half = pattern row i.
// Anti-diagonal t = i + j, t in [0, 1054]. One shfl_up per step carries
// D[i-1, *] down the lanes; previous step's shfl doubles as D[i-1,j-1].

#define BIGF 1e30f
#define DD   12
#define PP   32
#define LL   1024
#define LOUT 32

typedef float v4f __attribute__((ext_vector_type(4)));

__device__ __forceinline__ float cost12(const v4f p[3], const float xv[12]) {
    v4f x0 = {xv[0], xv[1], xv[2],  xv[3]};
    v4f x1 = {xv[4], xv[5], xv[6],  xv[7]};
    v4f x2 = {xv[8], xv[9], xv[10], xv[11]};
    v4f d0 = p[0] - x0;
    v4f d1 = p[1] - x1;
    v4f d2 = p[2] - x2;
    v4f acc = d0 * d0;
    acc = __builtin_elementwise_fma(d1, d1, acc);
    acc = __builtin_elementwise_fma(d2, d2, acc);
    return (acc.x + acc.y) + (acc.z + acc.w);
}

// One DP step. Reads all lanes' pre-update dprev via shfl (wave-synchronous),
// then updates dprev. Returns the raw new value (for the output store).
__device__ __forceinline__ float dp_step(float c, float& dprev, float& sh2,
                                         int li, bool valid) {
    float s   = __shfl_up(dprev, 1, 32);          // lane i-1's D at t-1
    float sh1 = (li == 0) ? BIGF : s;             // row -1 boundary
    float m   = fminf(fminf(sh2, sh1), dprev);    // min3 -> v_min3_f32
    float dv  = c + m;
    dprev = valid ? dv : BIGF;
    sh2   = sh1;                                  // becomes D[i-1,j-1] next step
    return dv;
}

__global__ __launch_bounds__(64) void dtw_kernel(const float* __restrict__ x,
                                                 const float* __restrict__ patts,
                                                 float* __restrict__ out) {
    const int lane = threadIdx.x;      // 0..63
    const int half = lane >> 5;        // which problem in this wave
    const int li   = lane & 31;        // pattern row i
    const int blk  = blockIdx.x;       // 0..511
    const int b    = blk >> 4;                 // 16 blocks per b
    const int n    = ((blk & 15) << 1) + half; // 2 n's per block

    const float* __restrict__ xb = x + b * (DD * LL);
    const float* __restrict__ pb = patts + n * (DD * PP);

    // pattern column li -> registers
    v4f p[3];
#pragma unroll
    for (int k = 0; k < 3; ++k) {
        float a0 = pb[(4 * k + 0) * PP + li];
        float a1 = pb[(4 * k + 1) * PP + li];
        float a2 = pb[(4 * k + 2) * PP + li];
        float a3 = pb[(4 * k + 3) * PP + li];
        v4f t = {a0, a1, a2, a3};
        p[k] = t;
    }

    __shared__ float lds_out[2 * PP * LOUT];   // 8 KB

    float dprev = BIGF;
    float sh2   = (li == 0) ? 0.0f : BIGF;     // makes D[0,0] = c[0,0]
    int   jj    = -li;                         // j = t - i

    // ---------- prologue: t = 0..31 (ramp-in, blocking loads) ----------
#pragma unroll 1
    for (int t = 0; t < 32; ++t) {
        int jc = jj > 0 ? jj : 0;
        float xv[12];
#pragma unroll
        for (int d = 0; d < DD; ++d) xv[d] = xb[d * LL + jc];
        float c = cost12(p, xv);
        (void)dp_step(c, dprev, sh2, li, jj >= 0);
        ++jj;
    }
    // jj == 32 - li here; all lanes valid from now through t=991.

    // prime the 2-deep load pipeline
    float X0[12], X1[12];
#pragma unroll
    for (int d = 0; d < DD; ++d) X0[d] = xb[d * LL + jj];
#pragma unroll
    for (int d = 0; d < DD; ++d) X1[d] = xb[d * LL + jj + 1];

    // ---------- steady: t = 32..991, no bounds checks, no stores ----------
#pragma unroll 1
    for (int t = 32; t < 992; t += 2) {
        // step A: consume X0 (x column jj), refill for jj+2
        {
            float c = cost12(p, X0);
#pragma unroll
            for (int d = 0; d < DD; ++d) X0[d] = xb[d * LL + (jj + 2)];
            (void)dp_step(c, dprev, sh2, li, true);
            ++jj;
        }
        // step B: consume X1, refill for jj+2
        {
            float c = cost12(p, X1);
#pragma unroll
            for (int d = 0; d < DD; ++d) X1[d] = xb[d * LL + (jj + 2)];
            (void)dp_step(c, dprev, sh2, li, true);
            ++jj;
        }
    }

    // ---------- epilogue: t = 992..1055 (clamped loads, predicated store) ----------
#pragma unroll 1
    for (int t = 992; t < 1056; t += 2) {
        {
            float c = cost12(p, X0);
            int jl = jj + 2; jl = jl > (LL - 1) ? (LL - 1) : jl;
#pragma unroll
            for (int d = 0; d < DD; ++d) X0[d] = xb[d * LL + jl];
            bool valid = (jj <= LL - 1);
            float dv = dp_step(c, dprev, sh2, li, valid);
            if (valid && jj >= LL - LOUT)
                lds_out[half * (PP * LOUT) + li * LOUT + (jj - (LL - LOUT))] = dv;
            ++jj;
        }
        {
            float c = cost12(p, X1);
            int jl = jj + 2; jl = jl > (LL - 1) ? (LL - 1) : jl;
#pragma unroll
            for (int d = 0; d < DD; ++d) X1[d] = xb[d * LL + jl];
            bool valid = (jj <= LL - 1);
            float dv = dp_step(c, dprev, sh2, li, valid);
            if (valid && jj >= LL - LOUT)
                lds_out[half * (PP * LOUT) + li * LOUT + (jj - (LL - LOUT))] = dv;
            ++jj;
        }
    }

    // ---------- coalesced flush: 2048 floats per block ----------
    __syncthreads();
    float* ob = out + blk * (2 * PP * LOUT);
#pragma unroll
    for (int r = 0; r < 32; ++r) ob[r * 64 + lane] = lds_out[r * 64 + lane];
}

extern "C" void kernel_launch(void* const* d_in, const int* in_sizes, int n_in,
                              void* d_out, int out_size, void* d_ws, size_t ws_size,
                              hipStream_t stream) {
    const float* x     = (const float*)d_in[0];   // [32,12,1024] f32
    const float* patts = (const float*)d_in[1];   // [32,12,32]   f32
    float* out         = (float*)d_out;           // [32,32,32,32] f32
    dtw_kernel<<<dim3(512), dim3(64), 0, stream>>>(x, patts, out);
}

// Round 2
// 127.049 us; speedup vs baseline: 1.9812x; 1.9812x over previous
//
#include <hip/hip_runtime.h>

// DTW wavefront kernel for MI355X (gfx950). Round 2.
// B=32, N=32, D=12, P=32, L=1024, L_OUT=32, RHO=1 => w=1 exactly.
// D[i,j] = c[i,j] + min3(D[i-1,j-1], D[i-1,j], D[i,j-1]); boundaries = BIG.
// One wave64 = 2 (b,n) problems (same b); lane-in-half = pattern row i.
// Changes vs round 1 (205 us, latency-bound):
//  - shfl_up (ds_bpermute, ~100cyc on chain) -> v_mov_b32 dpp wave_shr:1 (VALU)
//  - 12 global dword loads/step -> x[b] transposed in LDS, 3 ds_read_b128/step
//  - 4-deep software pipeline on the cost-column loads

#define BIGF 1e30f
#define DD   12
#define PP   32
#define LL   1024
#define LOUT 32
#define XPAD 12          // floats per LDS column (48B, 16B-aligned for b128)
#define PIPE 4

typedef float v4f __attribute__((ext_vector_type(4)));

__device__ __forceinline__ float wshr1(float v) {
    // full-wave shift down by one lane: lane i <- lane i-1 (lane 0 <- old=0)
    int r = __builtin_amdgcn_update_dpp(0, __float_as_int(v), 0x138 /*wave_shr:1*/,
                                        0xF, 0xF, false);
    return __int_as_float(r);
}

__device__ __forceinline__ float cost12v(const v4f p[3], const v4f xv[3]) {
    v4f d0 = p[0] - xv[0];
    v4f d1 = p[1] - xv[1];
    v4f d2 = p[2] - xv[2];
    v4f acc = d0 * d0;
    acc = __builtin_elementwise_fma(d1, d1, acc);
    acc = __builtin_elementwise_fma(d2, d2, acc);
    return (acc.x + acc.y) + (acc.z + acc.w);
}

__device__ __forceinline__ float dp_step(float c, float& dprev, float& sh2,
                                         bool lane0, bool valid) {
    float s   = wshr1(dprev);                 // lane i-1's D at t-1
    float sh1 = lane0 ? BIGF : s;             // row -1 boundary (both halves)
    float m   = fminf(fminf(sh2, sh1), dprev);
    float dv  = c + m;
    dprev = valid ? dv : BIGF;
    sh2   = sh1;                              // becomes D[i-1,j-1] next step
    return dv;
}

__global__ __launch_bounds__(64) void dtw_kernel(const float* __restrict__ x,
                                                 const float* __restrict__ patts,
                                                 float* __restrict__ out) {
    const int lane = threadIdx.x;      // 0..63
    const int half = lane >> 5;        // which problem in this wave
    const int li   = lane & 31;        // pattern row i
    const bool lane0 = (li == 0);
    const int blk  = blockIdx.x;       // 0..511
    const int b    = blk >> 4;                 // 16 blocks per b
    const int n    = ((blk & 15) << 1) + half; // 2 n's per block

    __shared__ alignas(16) float xs[LL * XPAD];          // 48 KB: xs[j*12+d]
    __shared__ alignas(16) float lds_out[2 * PP * LOUT]; // 8 KB

    // ---------- stage x[b] transposed into LDS ----------
    const float* __restrict__ xb = x + b * (DD * LL);
#pragma unroll 1
    for (int it = 0; it < 4; ++it) {
        int j0 = it * 256 + lane * 4;          // 4 consecutive columns per lane
        float vals[DD][4];
#pragma unroll
        for (int d = 0; d < DD; ++d) {
            v4f v = *(const v4f*)(xb + d * LL + j0);   // coalesced 16B/lane
            vals[d][0] = v.x; vals[d][1] = v.y; vals[d][2] = v.z; vals[d][3] = v.w;
        }
#pragma unroll
        for (int k = 0; k < 4; ++k) {
            v4f w0 = {vals[0][k], vals[1][k], vals[2][k],  vals[3][k]};
            v4f w1 = {vals[4][k], vals[5][k], vals[6][k],  vals[7][k]};
            v4f w2 = {vals[8][k], vals[9][k], vals[10][k], vals[11][k]};
            float* dst = &xs[(j0 + k) * XPAD];
            *(v4f*)(dst + 0) = w0;
            *(v4f*)(dst + 4) = w1;
            *(v4f*)(dst + 8) = w2;
        }
    }
    __syncthreads();   // single wave: compiles to waitcnt (+barrier), cheap

    // ---------- pattern column li -> registers ----------
    const float* __restrict__ pb = patts + n * (DD * PP);
    v4f p[3];
#pragma unroll
    for (int k = 0; k < 3; ++k) {
        float a0 = pb[(4 * k + 0) * PP + li];
        float a1 = pb[(4 * k + 1) * PP + li];
        float a2 = pb[(4 * k + 2) * PP + li];
        float a3 = pb[(4 * k + 3) * PP + li];
        v4f t = {a0, a1, a2, a3};
        p[k] = t;
    }

    float dprev = BIGF;
    float sh2   = lane0 ? 0.0f : BIGF;     // makes D[0,0] = c[0,0]
    int   jj    = -li;                     // j = t - i

    // prime the 4-deep pipeline (columns jj..jj+3, clamped low)
    v4f X[PIPE][3];
#pragma unroll
    for (int k = 0; k < PIPE; ++k) {
        int jc = jj + k; jc = jc < 0 ? 0 : jc;       // <= 3, in range
        const float* s = &xs[jc * XPAD];
        X[k][0] = *(const v4f*)(s + 0);
        X[k][1] = *(const v4f*)(s + 4);
        X[k][2] = *(const v4f*)(s + 8);
    }

    // ---------- prologue: t = 0..31 (validity check, clamped refill) ----------
#pragma unroll 1
    for (int t8 = 0; t8 < 8; ++t8) {
#pragma unroll
        for (int ph = 0; ph < PIPE; ++ph) {
            float c = cost12v(p, X[ph]);
            int jf = jj + PIPE; jf = jf < 0 ? 0 : jf;   // <= 35, in range
            const float* s = &xs[jf * XPAD];
            X[ph][0] = *(const v4f*)(s + 0);
            X[ph][1] = *(const v4f*)(s + 4);
            X[ph][2] = *(const v4f*)(s + 8);
            (void)dp_step(c, dprev, sh2, lane0, jj >= 0);
            ++jj;
        }
    }

    // ---------- steady: t = 32..991, no checks, no stores ----------
#pragma unroll 1
    for (int t4 = 0; t4 < 240; ++t4) {
#pragma unroll
        for (int ph = 0; ph < PIPE; ++ph) {
            float c = cost12v(p, X[ph]);
            const float* s = &xs[(jj + PIPE) * XPAD];
            X[ph][0] = *(const v4f*)(s + 0);
            X[ph][1] = *(const v4f*)(s + 4);
            X[ph][2] = *(const v4f*)(s + 8);
            (void)dp_step(c, dprev, sh2, lane0, true);
            ++jj;
        }
    }

    // ---------- epilogue: t = 992..1055 (clamped refill, predicated store) ----
#pragma unroll 1
    for (int t4 = 0; t4 < 16; ++t4) {
#pragma unroll
        for (int ph = 0; ph < PIPE; ++ph) {
            float c = cost12v(p, X[ph]);
            int jf = jj + PIPE; jf = jf > (LL - 1) ? (LL - 1) : jf;
            const float* s = &xs[jf * XPAD];
            X[ph][0] = *(const v4f*)(s + 0);
            X[ph][1] = *(const v4f*)(s + 4);
            X[ph][2] = *(const v4f*)(s + 8);
            bool valid = (jj <= LL - 1);
            float dv = dp_step(c, dprev, sh2, lane0, valid);
            if (valid && jj >= LL - LOUT)
                lds_out[half * (PP * LOUT) + li * LOUT + (jj - (LL - LOUT))] = dv;
            ++jj;
        }
    }

    // ---------- coalesced flush: 2048 floats per block ----------
    __syncthreads();
    float* ob = out + blk * (2 * PP * LOUT);
#pragma unroll
    for (int r = 0; r < 8; ++r) {
        v4f v = *(const v4f*)(&lds_out[r * 256 + lane * 4]);
        *(v4f*)(ob + r * 256 + lane * 4) = v;
    }
}

extern "C" void kernel_launch(void* const* d_in, const int* in_sizes, int n_in,
                              void* d_out, int out_size, void* d_ws, size_t ws_size,
                              hipStream_t stream) {
    const float* x     = (const float*)d_in[0];   // [32,12,1024] f32
    const float* patts = (const float*)d_in[1];   // [32,12,32]   f32
    float* out         = (float*)d_out;           // [32,32,32,32] f32
    dtw_kernel<<<dim3(512), dim3(64), 0, stream>>>(x, patts, out);
}

// Round 3
// 116.092 us; speedup vs baseline: 2.1682x; 1.0944x over previous
//
#include <hip/hip_runtime.h>

// DTW wavefront kernel for MI355X (gfx950). Round 3.
// B=32, N=32, D=12, P=32, L=1024, L_OUT=32, RHO=1 => w=1.
// D[i,j] = c[i,j] + min3(D[i-1,j-1], D[i-1,j], D[i,j-1]).
// One wave64 = 2 (b,n) problems (same b); lane-in-half = pattern row i.
// Round-3 structure: cost tiles (64 rows x 64 cols) produced by MFMA
// (bf16 cross term, fp32 p2/x2 fused in epilogue) into a 2-chunk LDS ring;
// DP inner loop reads 1 cost float/step (ds_read_b32) + ~8 VALU.
// x chunk for tile s+1 is prefetched into regs during DP segment s.

#define BIGF 1e30f
#define LL   1024
#define LOUT 32
#define CW   64          // chunk width (columns)
#define RSTR 132         // cbuf row stride in floats (2*64 ring + 4 pad)
#define NSEG 16

using v4f   = __attribute__((ext_vector_type(4))) float;
using s16x8 = __attribute__((ext_vector_type(8))) short;   // 8 bf16 in 4 VGPRs

__device__ __forceinline__ float wshr1(float v) {
    // whole-wave shift: lane i <- lane i-1 (lane 0 <- 0), pure VALU dpp
    int r = __builtin_amdgcn_update_dpp(0, __float_as_int(v), 0x138 /*wave_shr:1*/,
                                        0xF, 0xF, false);
    return __int_as_float(r);
}

__device__ __forceinline__ short f2bf(float f) {   // fp32 -> bf16 RNE
    unsigned u = __float_as_uint(f);
    u += 0x7FFF + ((u >> 16) & 1);
    return (short)(u >> 16);
}

// MODE 0: ramp-in (j<0 masked). 1: steady. 2: steady + output stores.
// 3: tail (stores only; invalid lanes' dprev is never consumed afterwards).
template<int MODE, int LEN>
__device__ __forceinline__ void dp_seg(const float* crow, float* lds_out,
                                       int outbase, bool lane0,
                                       int& jj, float& dprev, float& sh2) {
    float cr[8];
#pragma unroll
    for (int k = 0; k < 8; ++k) cr[k] = crow[(jj + k) & 127];   // prime pipeline
#pragma unroll 1
    for (int it = 0; it < LEN; it += 8) {
#pragma unroll
        for (int u = 0; u < 8; ++u) {
            float c = cr[u];
            cr[u] = crow[(jj + 8) & 127];          // refill 8 steps ahead
            float s   = wshr1(dprev);
            float sh1 = lane0 ? BIGF : s;
            float m   = fminf(fminf(sh2, sh1), dprev);   // v_min3_f32
            float dv  = c + m;
            bool valid = (MODE == 0) ? (jj >= 0) : true;
            dprev = valid ? dv : BIGF;
            sh2   = sh1;
            if (MODE >= 2) {
                unsigned jo = (unsigned)(jj - (LL - LOUT));
                if (jo < (unsigned)LOUT) lds_out[outbase + jo] = dv;
            }
            ++jj;
        }
    }
}

__global__ __launch_bounds__(64) void dtw_kernel(const float* __restrict__ x,
                                                 const float* __restrict__ patts,
                                                 float* __restrict__ out) {
    __shared__ float cbuf[64 * RSTR];          // 33 KB cost ring (2 chunks)
    __shared__ float x2s[LL];                  // 4 KB
    __shared__ float p2s[64];                  // 256 B
    __shared__ float lds_out[2 * 32 * LOUT];   // 8 KB

    const int lane = threadIdx.x;
    const int li   = lane & 31;
    const int q    = lane >> 4;       // mfma quad
    const int c16  = lane & 15;
    const bool lane0 = (li == 0);
    const int blk = blockIdx.x;
    const int b   = blk >> 4;
    const int n0  = (blk & 15) << 1;

    const float* __restrict__ xb = x + b * (12 * LL);

    // ---- x2s[j] = sum_d x[b][d][j]^2 (coalesced, one-time) ----
#pragma unroll 1
    for (int k = 0; k < 16; ++k) {
        int col = k * 64 + lane;
        float acc = 0.f;
#pragma unroll
        for (int d = 0; d < 12; ++d) { float v = xb[d * LL + col]; acc += v * v; }
        x2s[col] = acc;
    }

    // ---- p2s[r], r = n_local*32 + i : lane r computes its own ----
    {
        const float* pn = patts + (n0 + (lane >> 5)) * (12 * 32);
        float acc = 0.f;
#pragma unroll
        for (int d = 0; d < 12; ++d) { float v = pn[d * 32 + li]; acc += v * v; }
        p2s[lane] = acc;
    }

    // ---- A fragments: A[row = 16m + (lane&15)][k = q*8+e], k>=12 -> 0 ----
    s16x8 afrag[4];
#pragma unroll
    for (int m = 0; m < 4; ++m) {
        int row = 16 * m + c16;
        const float* pn = patts + (n0 + (row >> 5)) * (12 * 32);
        int i = row & 31;
#pragma unroll
        for (int e = 0; e < 8; ++e) {
            int d = q * 8 + e;
            float v = 0.f;
            if (d < 12) v = pn[d * 32 + i];
            afrag[m][e] = f2bf(v);
        }
    }

    // ---- p2r[m][r] = p2[16m + 4q + r] (C-frag row map) ----
    float p2r[4][4];
#pragma unroll
    for (int m = 0; m < 4; ++m)
#pragma unroll
        for (int r = 0; r < 4; ++r) p2r[m][r] = p2s[16 * m + q * 4 + r];

    // ---- DP state ----
    float dprev = BIGF;
    float sh2   = lane0 ? 0.0f : BIGF;   // yields D[0,0] = c[0,0]
    int   jj    = -li;                   // lane's own j = t - li
    const float* crow = cbuf + lane * RSTR;
    const int outbase = (lane >> 5) * (32 * LOUT) + li * LOUT;

    // ---- prefetch x chunk 0 into regs (B-frag order) ----
    float xpre[4][8];
#pragma unroll
    for (int tl = 0; tl < 4; ++tl)
#pragma unroll
        for (int e = 0; e < 8; ++e) {
            int d = q * 8 + e;
            float v = 0.f;
            if (d < 12) v = xb[d * LL + (16 * tl + c16)];
            xpre[tl][e] = v;
        }

#pragma unroll 1
    for (int s = 0; s < NSEG; ++s) {
        const int j0  = s * CW;
        const int par = (s & 1) * CW;     // ring half being written
        // ---- compute cost chunk s: 4 col-tiles x 4 row-tiles of 16x16 ----
#pragma unroll
        for (int tl = 0; tl < 4; ++tl) {
            s16x8 bfrag;
#pragma unroll
            for (int e = 0; e < 8; ++e) bfrag[e] = f2bf(xpre[tl][e]);
            float x2v = x2s[j0 + 16 * tl + c16];
            int colin = par + 16 * tl + c16;
#pragma unroll
            for (int m = 0; m < 4; ++m) {
                v4f z = {0.f, 0.f, 0.f, 0.f};
                v4f acc = __builtin_amdgcn_mfma_f32_16x16x32_bf16(afrag[m], bfrag, z, 0, 0, 0);
                // C-frag: col = lane&15, row = 16m + 4q + r
                float* wb = &cbuf[(16 * m + q * 4) * RSTR + colin];
#pragma unroll
                for (int r = 0; r < 4; ++r)
                    wb[r * RSTR] = p2r[m][r] + x2v - 2.0f * acc[r];
            }
        }
        // ---- prefetch x chunk s+1 (consumed after next DP segment) ----
        if (s < NSEG - 1) {
            const int j1 = (s + 1) * CW;
#pragma unroll
            for (int tl = 0; tl < 4; ++tl)
#pragma unroll
                for (int e = 0; e < 8; ++e) {
                    int d = q * 8 + e;
                    float v = 0.f;
                    if (d < 12) v = xb[d * LL + (j1 + 16 * tl + c16)];
                    xpre[tl][e] = v;
                }
        }
        // ---- DP segment: 64 diagonal steps ----
        if (s == 0)                dp_seg<0, CW>(crow, lds_out, outbase, lane0, jj, dprev, sh2);
        else if (s == NSEG - 1)    dp_seg<2, CW>(crow, lds_out, outbase, lane0, jj, dprev, sh2);
        else                       dp_seg<1, CW>(crow, lds_out, outbase, lane0, jj, dprev, sh2);
    }
    // ---- tail: t = 1024..1055 (stores for upper lanes; extra steps inert) ----
    dp_seg<3, 32>(crow, lds_out, outbase, lane0, jj, dprev, sh2);

    // ---- coalesced flush ----
    __syncthreads();
    float* ob = out + blk * (2 * 32 * LOUT);
#pragma unroll
    for (int r = 0; r < 8; ++r) {
        v4f v = *(const v4f*)(&lds_out[r * 256 + lane * 4]);
        *(v4f*)(ob + r * 256 + lane * 4) = v;
    }
}

extern "C" void kernel_launch(void* const* d_in, const int* in_sizes, int n_in,
                              void* d_out, int out_size, void* d_ws, size_t ws_size,
                              hipStream_t stream) {
    const float* x     = (const float*)d_in[0];   // [32,12,1024] f32
    const float* patts = (const float*)d_in[1];   // [32,12,32]   f32
    float* out         = (float*)d_out;           // [32,32,32,32] f32
    dtw_kernel<<<dim3(512), dim3(64), 0, stream>>>(x, patts, out);
}

// Round 4
// 96.424 us; speedup vs baseline: 2.6104x; 1.2040x over previous
//
#include <hip/hip_runtime.h>

// DTW wavefront kernel for MI355X (gfx950). Round 4.
// B=32, N=32, D=12, P=32, L=1024, L_OUT=32, RHO=1 => w=1.
// D[i,j] = c[i,j] + min3(D[i-1,j-1], D[i-1,j], D[i,j-1]).
// Round-4 structure: producer/consumer wave specialization per block.
//   wave 0 (producer): MFMA cost chunks (bf16 cross + fp32 p2/x2 epilogue)
//                      into a 2-slot LDS ring, one chunk ahead.
//   wave 1 (consumer): pure DP wavefront, 1 ds_read_b32 + ~8 VALU per step.
// Sync: __syncthreads() per chunk (both waves). 512 blocks x 128 thr
// = 1024 waves = 4/CU (vs 2/CU in round 3) and phases overlap (m114).

#define BIGF 1e30f
#define LL   1024
#define LOUT 32
#define CW   64          // chunk width (columns)
#define RSTR 132         // cbuf row stride in floats (2*64 ring + 4 pad)
#define NSEG 16

using v4f   = __attribute__((ext_vector_type(4))) float;
using s16x8 = __attribute__((ext_vector_type(8))) short;   // 8 bf16

__device__ __forceinline__ float wshr1(float v) {
    // whole-wave shift: lane i <- lane i-1 (lane 0 <- old=0), VALU dpp
    int r = __builtin_amdgcn_update_dpp(0, __float_as_int(v), 0x138 /*wave_shr:1*/,
                                        0xF, 0xF, false);
    return __int_as_float(r);
}

__device__ __forceinline__ short f2bf(float f) {   // fp32 -> bf16 RNE
    unsigned u = __float_as_uint(f);
    u += 0x7FFF + ((u >> 16) & 1);
    return (short)(u >> 16);
}

// MODE 0: ramp-in (j<0 masked). 1: steady. 2: steady + output stores.
// 3: tail (stores only; invalid lanes' garbage never reaches valid lanes).
template<int MODE, int LEN>
__device__ __forceinline__ void dp_seg(const float* crow, float* lds_out,
                                       int outbase, bool lane0,
                                       int& jj, float& dprev, float& sh2) {
    float cr[8];
#pragma unroll
    for (int k = 0; k < 8; ++k) cr[k] = crow[(jj + k) & 127];   // prime
#pragma unroll 1
    for (int it = 0; it < LEN; it += 8) {
#pragma unroll
        for (int u = 0; u < 8; ++u) {
            float c = cr[u];
            cr[u] = crow[(jj + 8) & 127];          // refill 8 ahead
            float t1  = fminf(sh2, dprev);         // off the shuffle chain
            float s   = wshr1(dprev);
            float sh1 = lane0 ? BIGF : s;
            float m   = fminf(t1, sh1);
            float dv  = c + m;
            bool valid = (MODE == 0) ? (jj >= 0) : true;
            dprev = valid ? dv : BIGF;
            sh2   = sh1;
            if (MODE >= 2) {
                unsigned jo = (unsigned)(jj - (LL - LOUT));
                if (jo < (unsigned)LOUT) lds_out[outbase + jo] = dv;
            }
            ++jj;
        }
    }
}

__global__ __launch_bounds__(128) void dtw_kernel(const float* __restrict__ x,
                                                  const float* __restrict__ patts,
                                                  float* __restrict__ out) {
    __shared__ float cbuf[64 * RSTR];          // 33.8 KB cost ring (2 slots)
    __shared__ float x2s[LL];                  // 4 KB
    __shared__ float p2s[64];
    __shared__ float lds_out[2 * 32 * LOUT];   // 8 KB

    const int tid  = threadIdx.x;
    const int wid  = tid >> 6;        // 0 = producer, 1 = consumer
    const int lane = tid & 63;
    const int li   = lane & 31;
    const int half = lane >> 5;
    const int q    = lane >> 4;       // mfma quad (producer)
    const int c16  = lane & 15;
    const bool lane0 = (li == 0);
    const int blk = blockIdx.x;
    const int b   = blk >> 4;
    const int n0  = (blk & 15) << 1;

    const float* __restrict__ xb = x + b * (12 * LL);

    // ---- x2s[j] = sum_d x[b][d][j]^2, split across both waves, ILP x2 ----
#pragma unroll 1
    for (int k = 0; k < 8; k += 2) {
        int col0 = (wid * 8 + k) * 64 + lane;
        int col1 = col0 + 64;
        float a0 = 0.f, a1 = 0.f;
#pragma unroll
        for (int d = 0; d < 12; ++d) {
            float v = xb[d * LL + col0]; a0 += v * v;
            float w = xb[d * LL + col1]; a1 += w * w;
        }
        x2s[col0] = a0; x2s[col1] = a1;
    }

    // ---- producer-only setup ----
    s16x8 afrag[4];
    float p2r[4][4];
    float xpre[4][8];
    if (wid == 0) {
        // p2s[r], r = half*32 + li
        {
            const float* pn = patts + (n0 + half) * (12 * 32);
            float acc = 0.f;
#pragma unroll
            for (int d = 0; d < 12; ++d) { float v = pn[d * 32 + li]; acc += v * v; }
            p2s[lane] = acc;
        }
        // A frags: A[row = 16m + c16][k = q*8+e], k>=12 -> 0
#pragma unroll
        for (int m = 0; m < 4; ++m) {
            int row = 16 * m + c16;
            const float* pm = patts + (n0 + (row >> 5)) * (12 * 32);
            int i = row & 31;
#pragma unroll
            for (int e = 0; e < 8; ++e) {
                int d = q * 8 + e;
                afrag[m][e] = f2bf(d < 12 ? pm[d * 32 + i] : 0.f);
            }
        }
        // p2r[m][r] = p2[16m + 4q + r]  (C-frag row map; intra-wave LDS RAW)
#pragma unroll
        for (int m = 0; m < 4; ++m)
#pragma unroll
            for (int r = 0; r < 4; ++r) p2r[m][r] = p2s[16 * m + q * 4 + r];
        // prefetch x chunk 0 into regs (B-frag order)
#pragma unroll
        for (int tl = 0; tl < 4; ++tl)
#pragma unroll
            for (int e = 0; e < 8; ++e) {
                int d = q * 8 + e;
                xpre[tl][e] = (d < 12) ? xb[d * LL + (16 * tl + c16)] : 0.f;
            }
    }

    auto produce = [&](int c) {
        // snapshot current chunk to bf16 so xpre can be refilled
        s16x8 bf[4];
#pragma unroll
        for (int tl = 0; tl < 4; ++tl)
#pragma unroll
            for (int e = 0; e < 8; ++e) bf[tl][e] = f2bf(xpre[tl][e]);
        // prefetch chunk c+1 (consumed next produce call, >=1 chunk away)
        if (c + 1 < NSEG) {
            const int j1 = (c + 1) * CW;
#pragma unroll
            for (int tl = 0; tl < 4; ++tl)
#pragma unroll
                for (int e = 0; e < 8; ++e) {
                    int d = q * 8 + e;
                    if (d < 12) xpre[tl][e] = xb[d * LL + (j1 + 16 * tl + c16)];
                }
        }
        const int j0  = c * CW;
        const int par = (c & 1) * CW;
#pragma unroll
        for (int tl = 0; tl < 4; ++tl) {
            float x2v = x2s[j0 + 16 * tl + c16];
            int colin = par + 16 * tl + c16;
#pragma unroll
            for (int m = 0; m < 4; ++m) {
                v4f z = {0.f, 0.f, 0.f, 0.f};
                v4f acc = __builtin_amdgcn_mfma_f32_16x16x32_bf16(afrag[m], bf[tl], z, 0, 0, 0);
                // C-frag: col = lane&15, row = 16m + 4q + r
                float* wb = &cbuf[(16 * m + q * 4) * RSTR + colin];
#pragma unroll
                for (int r = 0; r < 4; ++r)
                    wb[r * RSTR] = p2r[m][r] + x2v - 2.0f * acc[r];
            }
        }
    };

    // ---- consumer DP state ----
    float dprev = BIGF;
    float sh2   = lane0 ? 0.0f : BIGF;   // yields D[0,0] = c[0,0]
    int   jj    = -li;
    const float* crow = cbuf + lane * RSTR;
    const int outbase = half * (32 * LOUT) + li * LOUT;

    __syncthreads();                 // x2s ready
    if (wid == 0) produce(0);
    __syncthreads();                 // slot 0 ready

#pragma unroll 1
    for (int s = 0; s < NSEG; ++s) {
        if (wid == 0) {
            if (s + 1 < NSEG) produce(s + 1);           // writes slot (s+1)&1
        } else {
            if (s == 0)
                dp_seg<0, CW>(crow, lds_out, outbase, lane0, jj, dprev, sh2);
            else if (s < NSEG - 1)
                dp_seg<1, CW>(crow, lds_out, outbase, lane0, jj, dprev, sh2);
            else {
                dp_seg<2, CW>(crow, lds_out, outbase, lane0, jj, dprev, sh2);
                dp_seg<3, 32>(crow, lds_out, outbase, lane0, jj, dprev, sh2);
            }
        }
        __syncthreads();
    }

    // ---- coalesced flush: 2048 floats, 128 threads ----
    float* ob = out + blk * (2 * 32 * LOUT);
#pragma unroll
    for (int r = 0; r < 4; ++r) {
        int idx = r * 512 + tid * 4;
        v4f v = *(const v4f*)(&lds_out[idx]);
        *(v4f*)(ob + idx) = v;
    }
}

extern "C" void kernel_launch(void* const* d_in, const int* in_sizes, int n_in,
                              void* d_out, int out_size, void* d_ws, size_t ws_size,
                              hipStream_t stream) {
    const float* x     = (const float*)d_in[0];   // [32,12,1024] f32
    const float* patts = (const float*)d_in[1];   // [32,12,32]   f32
    float* out         = (float*)d_out;           // [32,32,32,32] f32
    dtw_kernel<<<dim3(512), dim3(128), 0, stream>>>(x, patts, out);
}